// Round 8
// baseline (227.495 us; speedup 1.0000x reference)
//
#include <hip/hip_runtime.h>

// SparseNeuralNetwork: 256 independent sub-nets j = i*16 + o (i,o in [0,16)).
//   layer0: v[k] = relu(W0[16j+k, i] * x[b,i] + b0[16j+k]),   k in [0,16)
//   layer1: u[m] = relu(b1[8j+m] + sum_k W1[8j+m, 16j+k] * v[k]), m in [0,8)
//   out[b,o] = b2[o] + sum_i sum_m W2[o, 8j+m] * u[m]
//
// R8: single launch. Block = 4 waves, one o-group (4 o's); block stages its
// 64 sub-net slots (45 KB) into LDS cooperatively, each lane then owns one
// slot's 176 weights in VGPRs (one-time 44 ds_read_b128). Batch loop is
// register-resident, 2 elems per step as float2 -> v_pk_fma_f32 (dual fp32).
// i-reduction = 4-step shfl_xor butterfly over lane bits 2..5.
// Grid 512 blocks = 2 blocks/CU = 2 waves/SIMD (VGPR ~240, LDS 46 KB x2).

#define BATCH   8192
#define IN_DIM  16
#define OUT_DIM 16
#define H0      16
#define H1      8
#define D0      (IN_DIM * OUT_DIM * H0)   // 4096
#define D1      (IN_DIM * OUT_DIM * H1)   // 2048
#define SLOT_PAD 180                       // 176 used; 180 breaks 32-bank stride

typedef float v2f __attribute__((ext_vector_type(2)));

__global__ __launch_bounds__(256, 2) void mlp_fused(
    const float* __restrict__ x,
    const float* __restrict__ W0, const float* __restrict__ b0,
    const float* __restrict__ W1, const float* __restrict__ b1,
    const float* __restrict__ W2, const float* __restrict__ b2,
    float* __restrict__ out)
{
    __shared__ float sW[64][SLOT_PAD];    // 46,080 B

    const int tid  = threadIdx.x;
    const int og   = blockIdx.x & 3;               // o-group: o = og*4 + (s&3)
    const int bb   = (blockIdx.x >> 2) * 64;       // 64 batch elems per block

    // ---- cooperative stage: 64 slots x 176 floats into LDS ----
    // slot s: i = s>>2, o = og*4 + (s&3), j = i*16 + o
    // layout per slot: [0..15] w0 | [16..31] b0 | [32..159] w1 (m-major) |
    //                  [160..167] b1 | [168..175] w2
    #pragma unroll
    for (int it = 0; it < 8; ++it) {               // W1: 2048 float4
        const int idx = it * 256 + tid;
        const int s = idx >> 5, q = idx & 31, m = q >> 2, p = q & 3;
        const int i = s >> 2, o = og * 4 + (s & 3), j = i * 16 + o;
        const float4 val = *(const float4*)(W1 + (size_t)(j * H1 + m) * D0 + j * H0 + p * 4);
        *(float4*)(&sW[s][32 + m * 16 + p * 4]) = val;
    }
    #pragma unroll
    for (int it = 0; it < 4; ++it) {               // W0 + b0: 1024 each
        const int idx = it * 256 + tid;
        const int s = idx >> 4, k = idx & 15;
        const int i = s >> 2, o = og * 4 + (s & 3), j = i * 16 + o;
        sW[s][k]      = W0[(j * H0 + k) * IN_DIM + i];
        sW[s][16 + k] = b0[j * H0 + k];
    }
    #pragma unroll
    for (int it = 0; it < 2; ++it) {               // b1 + w2: 512 each
        const int idx = it * 256 + tid;
        const int s = idx >> 3, m = idx & 7;
        const int i = s >> 2, o = og * 4 + (s & 3), j = i * 16 + o;
        sW[s][160 + m] = b1[j * H1 + m];
        sW[s][168 + m] = W2[o * D1 + j * H1 + m];
    }
    __syncthreads();

    // ---- one-time: lane's slot -> 176 VGPRs (44 ds_read_b128) ----
    const int lane = tid & 63;
    const int wv   = tid >> 6;
    float w[176];
    {
        const float4* __restrict__ lp = (const float4*)sW[lane];
        #pragma unroll
        for (int r = 0; r < 44; ++r) {
            const float4 q = lp[r];
            w[4*r] = q.x; w[4*r+1] = q.y; w[4*r+2] = q.z; w[4*r+3] = q.w;
        }
    }

    // ---- x preload: lane's column i, this wave's 16 batch elems ----
    const int i   = lane >> 2;
    const int bbw = bb + wv * 16;
    const float* __restrict__ xp = x + (size_t)bbw * IN_DIM + i;
    v2f xi[8];
    #pragma unroll
    for (int t = 0; t < 8; ++t)
        xi[t] = (v2f){xp[(2*t) * IN_DIM], xp[(2*t+1) * IN_DIM]};

    const float b2v = b2[og * 4 + (lane & 3)];

    // ---- register-resident compute: 8 float2 steps = 16 batch elems ----
    #pragma unroll
    for (int t = 0; t < 8; ++t) {
        const v2f xv = xi[t];
        v2f v[H0];
        #pragma unroll
        for (int k = 0; k < H0; ++k)
            v[k] = __builtin_elementwise_max(w[k] * xv + w[16 + k], (v2f)0.0f);

        v2f acc = (v2f)0.0f;
        #pragma unroll
        for (int m = 0; m < H1; ++m) {
            v2f u = (v2f)(w[160 + m]);
            #pragma unroll
            for (int k = 0; k < H0; ++k)
                u += w[32 + m * 16 + k] * v[k];
            acc += w[168 + m] * __builtin_elementwise_max(u, (v2f)0.0f);
        }

        // butterfly over i (lane bits 2..5); lanes 0..3 end with full sums
        float a0 = acc.x, a1 = acc.y;
        a0 += __shfl_xor(a0, 4, 64);  a1 += __shfl_xor(a1, 4, 64);
        a0 += __shfl_xor(a0, 8, 64);  a1 += __shfl_xor(a1, 8, 64);
        a0 += __shfl_xor(a0, 16, 64); a1 += __shfl_xor(a1, 16, 64);
        a0 += __shfl_xor(a0, 32, 64); a1 += __shfl_xor(a1, 32, 64);
        if (lane < 4) {
            out[(size_t)(bbw + 2*t)     * OUT_DIM + og * 4 + lane] = a0 + b2v;
            out[(size_t)(bbw + 2*t + 1) * OUT_DIM + og * 4 + lane] = a1 + b2v;
        }
    }
}

extern "C" void kernel_launch(void* const* d_in, const int* in_sizes, int n_in,
                              void* d_out, int out_size, void* d_ws, size_t ws_size,
                              hipStream_t stream) {
    const float* x  = (const float*)d_in[0];
    const float* W0 = (const float*)d_in[1];
    const float* b0 = (const float*)d_in[2];
    const float* W1 = (const float*)d_in[3];
    const float* b1 = (const float*)d_in[4];
    const float* W2 = (const float*)d_in[5];
    const float* b2 = (const float*)d_in[6];
    float* out = (float*)d_out;

    // 4 og x 128 batch-chunks = 512 blocks x 4 waves = 2048 waves
    mlp_fused<<<512, 256, 0, stream>>>(x, W0, b0, W1, b1, W2, b2, out);
}

// Round 9
// 119.898 us; speedup vs baseline: 1.8974x; 1.8974x over previous
//
#include <hip/hip_runtime.h>

// SparseNeuralNetwork: 256 independent sub-nets j = i*16 + o (i,o in [0,16)).
//   layer0: v[k] = relu(W0[16j+k, i] * x[b,i] + b0[16j+k]),   k in [0,16)
//   layer1: u[m] = relu(b1[8j+m] + sum_k W1[8j+m, 16j+k] * v[k]), m in [0,8)
//   out[b,o] = b2[o] + sum_i sum_m W2[o, 8j+m] * u[m]
//
// R9: register-resident weights WITHOUT the R8 spill. Each sub-net is split
// across 2 lanes by output-neuron half: lane = (i, o2, h) holds w0/b0 (dup),
// its 4 w1 rows, b1/w2 quarter -> 104 weight VGPRs (R8: 176 -> spilled at
// v2f pressure). Wave = 2 o x 16 i x 2 h; batch loop is 16 x v2f (pk_fma),
// fully register-resident; i+h reduction = 5-step shfl_xor butterfly
// (masks 1,4,8,16,32; bit1=o2 preserved). Single launch, no LDS, no ws.
// Peak live ~190 VGPR < 256 cap at __launch_bounds__(64,2).

#define BATCH   8192
#define IN_DIM  16
#define OUT_DIM 16
#define H0      16
#define H1      8
#define D0      (IN_DIM * OUT_DIM * H0)   // 4096
#define D1      (IN_DIM * OUT_DIM * H1)   // 2048

typedef float v2f __attribute__((ext_vector_type(2)));

__global__ __launch_bounds__(64, 2) void mlp_fused(
    const float* __restrict__ x,
    const float* __restrict__ W0, const float* __restrict__ b0,
    const float* __restrict__ W1, const float* __restrict__ b1,
    const float* __restrict__ W2, const float* __restrict__ b2,
    float* __restrict__ out)
{
    const int l  = threadIdx.x;             // 0..63
    const int og = blockIdx.x & 7;          // o-pair group
    const int bb = (blockIdx.x >> 3) * 32;  // 32 batch elems per wave

    const int h  = l & 1;                   // w1-row half
    const int o2 = (l >> 1) & 1;
    const int i  = l >> 2;
    const int o  = og * 2 + o2;
    const int j  = i * 16 + o;

    // ---- one-time: this lane's weight quarter -> VGPRs ----
    float w0[16], bb0[16], w1[4][16], bb1[4], w2[4];
    #pragma unroll
    for (int k = 0; k < 16; ++k)
        w0[k] = W0[(j * H0 + k) * IN_DIM + i];        // col-i gather
    {
        const float4* p = (const float4*)(b0 + j * H0);  // contiguous
        #pragma unroll
        for (int q = 0; q < 4; ++q) {
            const float4 t = p[q];
            bb0[4*q] = t.x; bb0[4*q+1] = t.y; bb0[4*q+2] = t.z; bb0[4*q+3] = t.w;
        }
    }
    #pragma unroll
    for (int mm = 0; mm < 4; ++mm) {        // 4 contiguous rows of 16
        const float4* p = (const float4*)(W1 + (size_t)(j * H1 + h * 4 + mm) * D0 + j * H0);
        #pragma unroll
        for (int q = 0; q < 4; ++q) {
            const float4 t = p[q];
            w1[mm][4*q] = t.x; w1[mm][4*q+1] = t.y; w1[mm][4*q+2] = t.z; w1[mm][4*q+3] = t.w;
        }
    }
    {
        const float4 t1 = *(const float4*)(b1 + j * H1 + h * 4);
        bb1[0] = t1.x; bb1[1] = t1.y; bb1[2] = t1.z; bb1[3] = t1.w;
        const float4 t2 = *(const float4*)(W2 + o * D1 + j * H1 + h * 4);
        w2[0] = t2.x; w2[1] = t2.y; w2[2] = t2.z; w2[3] = t2.w;
    }

    // ---- x preload: lane's column i for its 32 batch elems ----
    v2f xi[16];
    {
        const float* __restrict__ xp = x + (size_t)bb * IN_DIM + i;
        #pragma unroll
        for (int t = 0; t < 16; ++t)
            xi[t] = (v2f){xp[(2*t) * IN_DIM], xp[(2*t+1) * IN_DIM]};
    }

    const float b2v = b2[o];

    // ---- register-resident compute: 16 x v2f steps = 32 batch elems ----
    #pragma unroll
    for (int t = 0; t < 16; ++t) {
        const v2f xv = xi[t];
        v2f v[H0];
        #pragma unroll
        for (int k = 0; k < H0; ++k)
            v[k] = __builtin_elementwise_max(w0[k] * xv + bb0[k], (v2f)0.0f);

        v2f acc = (v2f)0.0f;
        #pragma unroll
        for (int mm = 0; mm < 4; ++mm) {
            v2f u = (v2f)(bb1[mm]);
            #pragma unroll
            for (int k = 0; k < H0; ++k)
                u += w1[mm][k] * v[k];
            acc += w2[mm] * __builtin_elementwise_max(u, (v2f)0.0f);
        }

        // butterfly over h (bit0) and i (bits 2..5); bit1 (o2) preserved
        float a0 = acc.x, a1 = acc.y;
        a0 += __shfl_xor(a0, 1, 64);  a1 += __shfl_xor(a1, 1, 64);
        a0 += __shfl_xor(a0, 4, 64);  a1 += __shfl_xor(a1, 4, 64);
        a0 += __shfl_xor(a0, 8, 64);  a1 += __shfl_xor(a1, 8, 64);
        a0 += __shfl_xor(a0, 16, 64); a1 += __shfl_xor(a1, 16, 64);
        a0 += __shfl_xor(a0, 32, 64); a1 += __shfl_xor(a1, 32, 64);
        if ((l & 61) == 0) {                 // lanes 0 (o2=0) and 2 (o2=1)
            out[(size_t)(bb + 2*t)     * OUT_DIM + o] = a0 + b2v;
            out[(size_t)(bb + 2*t + 1) * OUT_DIM + o] = a1 + b2v;
        }
    }
}

extern "C" void kernel_launch(void* const* d_in, const int* in_sizes, int n_in,
                              void* d_out, int out_size, void* d_ws, size_t ws_size,
                              hipStream_t stream) {
    const float* x  = (const float*)d_in[0];
    const float* W0 = (const float*)d_in[1];
    const float* b0 = (const float*)d_in[2];
    const float* W1 = (const float*)d_in[3];
    const float* b1 = (const float*)d_in[4];
    const float* W2 = (const float*)d_in[5];
    const float* b2 = (const float*)d_in[6];
    float* out = (float*)d_out;

    // 8 o-pairs x 256 batch-chunks = 2048 single-wave blocks (2 waves/SIMD)
    mlp_fused<<<2048, 64, 0, stream>>>(x, W0, b0, W1, b1, W2, b2, out);
}

// Round 10
// 102.369 us; speedup vs baseline: 2.2223x; 1.1712x over previous
//
#include <hip/hip_runtime.h>

// SparseNeuralNetwork: 256 independent sub-nets j = i*16 + o (i,o in [0,16)).
//   layer0: v[k] = relu(W0[16j+k, i] * x[b,i] + b0[16j+k]),   k in [0,16)
//   layer1: u[m] = relu(b1[8j+m] + sum_k W1[8j+m, 16j+k] * v[k]), m in [0,8)
//   out[b,o] = b2[o] + sum_i sum_m W2[o, 8j+m] * u[m]
//
// R10: single launch. Block (4 waves) serves one o-pair group og; it stages
// the og's weights into LDS in a TRANSPOSED per-lane layout (sW[26][64]
// float4) with aligned float4 global reads, then each lane pulls its private
// 104 weights (half-split: lane = i*4 + o2*2 + h; h owns W1 rows 4h..4h+3)
// via 26 conflict-free ds_read_b128. Compute is scalar fp32, fully register
// resident, 32 batch elems per wave; i+h reduction = 5-step shfl_xor
// butterfly (masks 1,4,8,16,32; bit1=o2 preserved). Live ~165 VGPR -> no
// spill (R8 spilled at 176w + v2f; R9's direct gather was latency-bound).
// Grid 8 og x 64 chunks = 512 blocks = 2048 waves = 2/SIMD.

#define BATCH   8192
#define IN_DIM  16
#define OUT_DIM 16
#define H0      16
#define H1      8
#define D0      (IN_DIM * OUT_DIM * H0)   // 4096
#define D1      (IN_DIM * OUT_DIM * H1)   // 2048

// per-lane weight vector (104 floats = 26 float4):
//   [0..15]  w0 (W0 col i)      [16..31] b0
//   [32..95] w1 rows h*4..h*4+3 (m-major, 16 each)
//   [96..99] b1[h*4..]          [100..103] w2[h*4..]
#define NR4 26

__global__ __launch_bounds__(256, 2) void mlp_fused(
    const float* __restrict__ x,
    const float* __restrict__ W0, const float* __restrict__ b0,
    const float* __restrict__ W1, const float* __restrict__ b1,
    const float* __restrict__ W2, const float* __restrict__ b2,
    float* __restrict__ out)
{
    __shared__ float4 sW[NR4][64];        // 26,624 B, transposed per-lane

    const int tid = threadIdx.x;
    const int og  = blockIdx.y;           // o-pair: o = og*2 + o2
    const int bb  = blockIdx.x * 128;     // 128 batch elems per block

    // ---- cooperative stage: slot s (0..63): h=s&1, o2=(s>>1)&1, i=s>>2 ----
    for (int idx = tid; idx < NR4 * 64; idx += 256) {
        const int s  = idx & 63, r4 = idx >> 6;
        const int h  = s & 1, o2 = (s >> 1) & 1, i = s >> 2;
        const int o  = og * 2 + o2;
        const int j  = i * 16 + o;
        float4 val;
        if (r4 < 4) {                      // w0: col-i gather (4 scalar)
            val.x = W0[(j * H0 + 4*r4    ) * IN_DIM + i];
            val.y = W0[(j * H0 + 4*r4 + 1) * IN_DIM + i];
            val.z = W0[(j * H0 + 4*r4 + 2) * IN_DIM + i];
            val.w = W0[(j * H0 + 4*r4 + 3) * IN_DIM + i];
        } else if (r4 < 8) {               // b0: aligned float4
            val = *(const float4*)(b0 + j * H0 + (r4 - 4) * 4);
        } else if (r4 < 24) {              // w1: row h*4+mm, quarter kq
            const int rr = r4 - 8, mm = rr >> 2, kq = rr & 3;
            val = *(const float4*)(W1 + (size_t)(j * H1 + h * 4 + mm) * D0
                                      + j * H0 + kq * 4);
        } else if (r4 == 24) {             // b1 quarter
            val = *(const float4*)(b1 + j * H1 + h * 4);
        } else {                           // w2 quarter
            val = *(const float4*)(W2 + o * D1 + j * H1 + h * 4);
        }
        sW[r4][s] = val;
    }
    __syncthreads();

    // ---- one-time: lane's 104 weights -> VGPRs (26 conflict-free b128) ----
    const int l  = tid & 63;
    const int wv = tid >> 6;
    float w[104];
    #pragma unroll
    for (int r4 = 0; r4 < NR4; ++r4) {
        const float4 q = sW[r4][l];
        w[4*r4] = q.x; w[4*r4+1] = q.y; w[4*r4+2] = q.z; w[4*r4+3] = q.w;
    }

    const int o2 = (l >> 1) & 1;
    const int i  = l >> 2;
    const int o  = og * 2 + o2;
    const int bbw = bb + wv * 32;          // this wave's 32 batch elems

    // ---- x preload: lane's column i ----
    float xi[32];
    {
        const float* __restrict__ xp = x + (size_t)bbw * IN_DIM + i;
        #pragma unroll
        for (int t = 0; t < 32; ++t) xi[t] = xp[t * IN_DIM];
    }

    const float b2v = b2[o];

    // ---- register-resident compute ----
    #pragma unroll
    for (int t = 0; t < 32; ++t) {
        const float xv = xi[t];
        float v[H0];
        #pragma unroll
        for (int k = 0; k < H0; ++k)
            v[k] = fmaxf(fmaf(w[k], xv, w[16 + k]), 0.0f);

        float acc = 0.0f;
        #pragma unroll
        for (int mm = 0; mm < 4; ++mm) {
            float u = w[96 + mm];
            #pragma unroll
            for (int k = 0; k < H0; ++k)
                u = fmaf(w[32 + mm * 16 + k], v[k], u);
            acc = fmaf(w[100 + mm], fmaxf(u, 0.0f), acc);
        }

        // butterfly over h (bit0) + i (bits 2..5); bit1 (o2) preserved
        acc += __shfl_xor(acc, 1, 64);
        acc += __shfl_xor(acc, 4, 64);
        acc += __shfl_xor(acc, 8, 64);
        acc += __shfl_xor(acc, 16, 64);
        acc += __shfl_xor(acc, 32, 64);
        if ((l & 61) == 0)                 // lanes 0 (o2=0), 2 (o2=1)
            out[(size_t)(bbw + t) * OUT_DIM + o] = acc + b2v;
    }
}

extern "C" void kernel_launch(void* const* d_in, const int* in_sizes, int n_in,
                              void* d_out, int out_size, void* d_ws, size_t ws_size,
                              hipStream_t stream) {
    const float* x  = (const float*)d_in[0];
    const float* W0 = (const float*)d_in[1];
    const float* b0 = (const float*)d_in[2];
    const float* W1 = (const float*)d_in[3];
    const float* b1 = (const float*)d_in[4];
    const float* W2 = (const float*)d_in[5];
    const float* b2 = (const float*)d_in[6];
    float* out = (float*)d_out;

    dim3 grid(BATCH / 128, 8);            // 64 chunks x 8 o-pairs = 512 blocks
    mlp_fused<<<grid, 256, 0, stream>>>(x, W0, b0, W1, b1, W2, b2, out);
}